// Round 13
// baseline (6151.793 us; speedup 1.0000x reference)
//
#include <hip/hip_runtime.h>
#include <math.h>

// x: (64,32,32,64) fp32 -> N=65536 rows, D=64; codebook K=1024 (256KB, L2-resident).
// Strategy: NO codebook LDS staging. k0 transposes cb -> cbT[64][1024] (k-major) in ws;
// k1 streams cbT directly from L2 with coalesced dwordx4 (64 lanes x 16B = 1KB/instr).
// z2 = S2*dot - H2S*||c||^2 = log2(e) * (-dist/T + const_row): softmax/argmax preserved.
// NOTE: HIP has NO __exp2f/__log2f device intrinsics (glibc macro collision at compile);
// use __builtin_exp2f/__builtin_log2f -> v_exp_f32/v_log_f32 (base-2 IS the native op).
// ws (floats): [0,65536) cbT; [65536,66560) hs2; [66560,+512*1024) partials; then 4 accs.
#define WS_CBT 0
#define WS_H2 65536
#define WS_PART 66560
#define WS_ACC (66560 + 512*1024)
#define LOSSOFF 4194304
#define IDXOFF  4194305
#define S2  288.53900817779268f   // 200*log2(e)
#define H2S 144.26950408889634f   // 100*log2(e)

__global__ void vq_k0(const float* __restrict__ cb, float* __restrict__ ws) {
  const int bid = blockIdx.x, tid = threadIdx.x;
  if (bid < 64) {                        // transpose: this block owns d = bid
    const int d = bid, k0 = tid << 2;
    float4 v;
    v.x = cb[(k0 + 0) * 64 + d];
    v.y = cb[(k0 + 1) * 64 + d];
    v.z = cb[(k0 + 2) * 64 + d];
    v.w = cb[(k0 + 3) * 64 + d];
    *(float4*)(ws + WS_CBT + d * 1024 + k0) = v;
  } else {                               // hs2 for k = (bid-64)*256 + tid
    const int k = ((bid - 64) << 8) + tid;
    const float4* row = (const float4*)(cb + (k << 6));
    float s = 0.f;
    #pragma unroll
    for (int i = 0; i < 16; ++i) {
      float4 v = row[i];
      s += v.x * v.x + v.y * v.y + v.z * v.z + v.w * v.w;
    }
    ws[WS_H2 + k] = H2S * s;
    if (bid == 64 && tid < 4) ws[WS_ACC + tid] = 0.f;
  }
}

// 32 rows/block (grid 2048), 4 waves; each wave owns 8 rows x all 1024 cols.
// Thread cols: col = j*256 + lane*4 + q (j=0..3, q=0..3) -> zb[8][16], all static.
__launch_bounds__(256, 2)
__global__ void vq_k1(const float* __restrict__ x, const float* __restrict__ cb,
                      float* __restrict__ out, float* __restrict__ ws) {
  __shared__ float xs[32 * 64];          // 8KB
  __shared__ float avgp[1024];           // 4KB
  __shared__ int   bestArr[32];
  __shared__ float entAcc;
  __shared__ float redQ[4];

  const int tid  = threadIdx.x;
  const int w    = tid >> 6;
  const int lane = tid & 63;
  const int row0 = blockIdx.x << 5;
  const int wrow = w << 3;               // wave's first local row

  #pragma unroll
  for (int q = 0; q < 2; ++q) {          // stage x tile
    const int idx = tid * 2 + q;
    const int r = idx >> 4, c16 = idx & 15;
    *(float4*)&xs[r * 64 + c16 * 4] = *(const float4*)(x + (size_t)(row0 + r) * 64 + c16 * 4);
  }
  ((float4*)avgp)[tid] = make_float4(0.f, 0.f, 0.f, 0.f);
  if (tid == 0) entAcc = 0.f;
  __syncthreads();

  float zb[8][16];
  #pragma unroll
  for (int r = 0; r < 8; ++r)
    #pragma unroll
    for (int cc = 0; cc < 16; ++cc) zb[r][cc] = 0.f;

  const float* cbase = ws + WS_CBT + (lane << 2);

  #pragma unroll
  for (int dq = 0; dq < 16; ++dq) {
    float4 xv[8];
    #pragma unroll
    for (int r = 0; r < 8; ++r)
      xv[r] = *(const float4*)&xs[(wrow + r) * 64 + dq * 4];    // broadcast LDS read
    #pragma unroll
    for (int di = 0; di < 4; ++di) {                            // d = dq*4+di ascending
      const float* p = cbase + (dq * 4 + di) * 1024;
      const float4 c0 = *(const float4*)(p);
      const float4 c1 = *(const float4*)(p + 256);
      const float4 c2 = *(const float4*)(p + 512);
      const float4 c3 = *(const float4*)(p + 768);
      #pragma unroll
      for (int r = 0; r < 8; ++r) {
        const float xd = (di == 0) ? xv[r].x : (di == 1) ? xv[r].y
                       : (di == 2) ? xv[r].z : xv[r].w;
        zb[r][ 0] += xd * c0.x; zb[r][ 1] += xd * c0.y; zb[r][ 2] += xd * c0.z; zb[r][ 3] += xd * c0.w;
        zb[r][ 4] += xd * c1.x; zb[r][ 5] += xd * c1.y; zb[r][ 6] += xd * c1.z; zb[r][ 7] += xd * c1.w;
        zb[r][ 8] += xd * c2.x; zb[r][ 9] += xd * c2.y; zb[r][10] += xd * c2.z; zb[r][11] += xd * c2.w;
        zb[r][12] += xd * c3.x; zb[r][13] += xd * c3.y; zb[r][14] += xd * c3.z; zb[r][15] += xd * c3.w;
      }
    }
  }

  // z2 = S2*dot - hs2[col]
  float hv[16];
  #pragma unroll
  for (int j = 0; j < 4; ++j) {
    const float4 h4 = *(const float4*)(ws + WS_H2 + j * 256 + (lane << 2));
    hv[j * 4 + 0] = h4.x; hv[j * 4 + 1] = h4.y; hv[j * 4 + 2] = h4.z; hv[j * 4 + 3] = h4.w;
  }
  #pragma unroll
  for (int r = 0; r < 8; ++r)
    #pragma unroll
    for (int cc = 0; cc < 16; ++cc) zb[r][cc] = fmaf(S2, zb[r][cc], -hv[cc]);

  // ---- pass 1: max + argmax (first-index tie-break; within-thread cols ascend) ----
  float mx[8]; int bidx[8];
  #pragma unroll
  for (int r = 0; r < 8; ++r) {
    float mm = zb[r][0]; int bi = (lane << 2);
    #pragma unroll
    for (int cc = 1; cc < 16; ++cc) {
      const int col = (cc >> 2) * 256 + (lane << 2) + (cc & 3);
      if (zb[r][cc] > mm) { mm = zb[r][cc]; bi = col; }
    }
    mx[r] = mm; bidx[r] = bi;
  }
  #pragma unroll
  for (int mk = 1; mk <= 32; mk <<= 1)
    #pragma unroll
    for (int r = 0; r < 8; ++r) {
      const float ov = __shfl_xor(mx[r], mk);
      const int   oi = __shfl_xor(bidx[r], mk);
      if (ov > mx[r] || (ov == mx[r] && oi < bidx[r])) { mx[r] = ov; bidx[r] = oi; }
    }

  // ---- pass 2: sum 2^(z-m) ----
  float ls[8] = {0.f,0.f,0.f,0.f,0.f,0.f,0.f,0.f};
  #pragma unroll
  for (int cc = 0; cc < 16; ++cc)
    #pragma unroll
    for (int r = 0; r < 8; ++r) ls[r] += __builtin_exp2f(zb[r][cc] - mx[r]);
  #pragma unroll
  for (int mk = 1; mk <= 32; mk <<= 1)
    #pragma unroll
    for (int r = 0; r < 8; ++r) ls[r] += __shfl_xor(ls[r], mk);
  float lse[8];
  #pragma unroll
  for (int r = 0; r < 8; ++r) lse[r] = mx[r] + __builtin_log2f(ls[r]);

  // ---- pass 3: p = 2^(z-lse); psz = sum p*z (per row); cs = sum_r p (per col) ----
  float psz[8] = {0.f,0.f,0.f,0.f,0.f,0.f,0.f,0.f};
  float cs[16];
  #pragma unroll
  for (int cc = 0; cc < 16; ++cc) cs[cc] = 0.f;
  #pragma unroll
  for (int cc = 0; cc < 16; ++cc)
    #pragma unroll
    for (int r = 0; r < 8; ++r) {
      const float p = __builtin_exp2f(zb[r][cc] - lse[r]);
      psz[r] += p * zb[r][cc];
      cs[cc] += p;
    }
  #pragma unroll
  for (int mk = 1; mk <= 32; mk <<= 1)
    #pragma unroll
    for (int r = 0; r < 8; ++r) psz[r] += __shfl_xor(psz[r], mk);

  if (lane == 0) {                       // entropy + indices for this wave's 8 rows
    float e = 0.f;
    #pragma unroll
    for (int r = 0; r < 8; ++r) {
      e += lse[r] - psz[r];              // base-2 units
      bestArr[wrow + r] = bidx[r];
      out[IDXOFF + row0 + wrow + r] = (float)bidx[r];
    }
    atomicAdd(&entAcc, e * 0.69314718055994531f);
  }

  #pragma unroll
  for (int cc = 0; cc < 16; ++cc)        // per-col prob sums (4-way wave contention)
    atomicAdd(&avgp[(cc >> 2) * 256 + (lane << 2) + (cc & 3)], cs[cc]);
  __syncthreads();                       // avgp + bestArr ready

  {                                      // flush partials (4 blocks share a slot)
    float* slot = ws + WS_PART + (size_t)(blockIdx.x & 511) * 1024;
    #pragma unroll
    for (int g = 0; g < 4; ++g) atomicAdd(&slot[g * 256 + tid], avgp[g * 256 + tid]);
  }

  // ---- epilogue: quantized STE output + squared-error ----
  float sq = 0.f;
  #pragma unroll
  for (int q = 0; q < 2; ++q) {
    const int idx = tid * 2 + q;
    const int r = idx >> 4, c16 = idx & 15;
    const int code = bestArr[r];
    const float4 c4 = *(const float4*)(cb + (size_t)code * 64 + c16 * 4);
    const float4 x4 = *(const float4*)&xs[r * 64 + c16 * 4];
    const float dx = c4.x - x4.x, dy = c4.y - x4.y, dz = c4.z - x4.z, dw = c4.w - x4.w;
    sq += dx * dx + dy * dy + dz * dz + dw * dw;
    float4 o;
    o.x = x4.x + dx; o.y = x4.y + dy; o.z = x4.z + dz; o.w = x4.w + dw;
    *(float4*)(out + (size_t)(row0 + r) * 64 + c16 * 4) = o;
  }
  #pragma unroll
  for (int mk = 1; mk <= 32; mk <<= 1) sq += __shfl_xor(sq, mk);
  if (lane == 0) redQ[w] = sq;
  __syncthreads();
  if (tid == 0) {
    atomicAdd(ws + WS_ACC + 0, redQ[0] + redQ[1] + redQ[2] + redQ[3]);
    atomicAdd(ws + WS_ACC + 1, entAcc);
  }
}

// Reduce 512 partial slots -> avg_probs -> avg_entropy.
__global__ void vq_k2(float* __restrict__ ws) {
  __shared__ float sh[8][32];
  const int t = threadIdx.x;
  const int bl = t >> 5, cl = t & 31;
  const int k = blockIdx.x * 32 + cl;    // grid 32
  float s = 0.f;
  #pragma unroll 4
  for (int i = 0; i < 64; ++i)
    s += ws[WS_PART + (size_t)((bl << 6) + i) * 1024 + k];
  sh[bl][cl] = s;
  __syncthreads();
  if (t < 32) {
    float tot = 0.f;
    #pragma unroll
    for (int b = 0; b < 8; ++b) tot += sh[b][t];
    const float p = tot * (1.f / 65536.f);
    float c = -p * __logf(p + 1e-5f);
    c += __shfl_xor(c, 1);
    c += __shfl_xor(c, 2);
    c += __shfl_xor(c, 4);
    c += __shfl_xor(c, 8);
    c += __shfl_xor(c, 16);
    if (t == 0) atomicAdd(ws + WS_ACC + 2, c);
  }
}

__global__ void vq_k3(const float* __restrict__ ws, float* __restrict__ out) {
  if (threadIdx.x == 0) {
    const float msq  = ws[WS_ACC + 0] * (1.f / (65536.f * 64.f));
    const float sent = ws[WS_ACC + 1] * (1.f / 65536.f);
    const float aent = ws[WS_ACC + 2];
    out[LOSSOFF] = 1.25f * msq + 0.1f * (sent - aent);
  }
}

extern "C" void kernel_launch(void* const* d_in, const int* in_sizes, int n_in,
                              void* d_out, int out_size, void* d_ws, size_t ws_size,
                              hipStream_t stream) {
  (void)in_sizes; (void)n_in; (void)out_size; (void)ws_size;
  const float* x  = (const float*)d_in[0];
  const float* cb = (const float*)d_in[1];
  float* out = (float*)d_out;
  float* ws  = (float*)d_ws;

  vq_k0<<<dim3(68), dim3(256), 0, stream>>>(cb, ws);
  (void)hipMemsetAsync(ws + WS_PART, 0, (size_t)512 * 1024 * sizeof(float), stream);
  vq_k1<<<dim3(2048), dim3(256), 0, stream>>>(x, cb, out, ws);
  vq_k2<<<dim3(32), dim3(256), 0, stream>>>(ws);
  vq_k3<<<dim3(1), dim3(64), 0, stream>>>(ws, out);
}